// Round 14
// baseline (200.497 us; speedup 1.0000x reference)
//
#include <hip/hip_runtime.h>

typedef unsigned int u32;
typedef u32 u32x4 __attribute__((ext_vector_type(4)));
typedef float f32x4 __attribute__((ext_vector_type(4)));

#define N_ROWS 2048
#define K_DIM  1024
#define K4     256          // u32 words per row
#define O_DIM  4096

#define QSCALE   23.090909f      // 127 / 5.5
#define QBIAS    128.5f          // +128 bias, +0.5 for round via trunc
#define INVSCALE (5.5f / 127.0f)

#define XWORDS (N_ROWS * K4)     // 524288 u32 (2 MB)
#define WWORDS (O_DIM * K4)      // 1048576 u32 (4 MB)

// v_sad_u8: D = sum_{i<4} |S0.byte[i] - S1.byte[i]| + S2  (4 cyc/wave-instr)
__device__ __forceinline__ u32 sad_u8(u32 a, u32 b, u32 c) {
  u32 d;
  asm("v_sad_u8 %0, %1, %2, %3" : "=v"(d) : "v"(a), "v"(b), "v"(c));
  return d;
}

__device__ __forceinline__ u32 quant4(f32x4 v) {
  u32 b0 = (u32)fminf(fmaxf(fmaf(v[0], QSCALE, QBIAS), 0.f), 255.f);
  u32 b1 = (u32)fminf(fmaxf(fmaf(v[1], QSCALE, QBIAS), 0.f), 255.f);
  u32 b2 = (u32)fminf(fmaxf(fmaf(v[2], QSCALE, QBIAS), 0.f), 255.f);
  u32 b3 = (u32)fminf(fmaxf(fmaf(v[3], QSCALE, QBIAS), 0.f), 255.f);
  return b0 | (b1 << 8) | (b2 << 16) | (b3 << 24);
}

__global__ void quant_both(const float* __restrict__ x, const float* __restrict__ w,
                           u32* __restrict__ qx, u32* __restrict__ qw) {
  int i = blockIdx.x * blockDim.x + threadIdx.x;
  if (i < XWORDS)
    qx[i] = quant4(((const f32x4*)x)[i]);
  else if (i < XWORDS + WWORDS)
    qw[i - XWORDS] = quant4(((const f32x4*)w)[i - XWORDS]);
}

#define GLL(src, dst)                                                     \
  __builtin_amdgcn_global_load_lds(                                       \
      (const __attribute__((address_space(1))) void*)(src),               \
      (__attribute__((address_space(3))) void*)(dst), 16, 0, 0)

// 2-wave blocks (128 thr), ONE 64n x 64o tile per block, thread tile 8x8 on
// lane (tx=lane&7, ty=lane>>3). Wave w computes c-phases {2w,2w+1} of every kt
// (split-K): partial acc merged via LDS at the end. Grid 2048 -> 4096 waves
// = 4 waves/SIMD (vs 2 before) -> TLP hides per-phase LDS latency without
// any intra-wave pipeline (which hipcc refuses to hold: R6/R8/R10/R13).
// LDS: 2 bufs x 8KB (x 4KB rows 64B | w 4KB rows 64B), KC=64B, 16 kts.
// Swizzle (verified 0 conflicts, R9/R13): LDS[r][s] = G[r][s ^ key(r)]:
//   x key (r>>3)&3 (read: ty&3), w key (r>>1)&3 (read: (tx>>1)&3).
// Staging: linear GLL dest + pre-permuted per-lane source; wave0 stages x
// (4 GLL), wave1 stages w (4 GLL). One __syncthreads per kt, placed AFTER
// compute so its implicit vmcnt(0) drains a ~2000-cycle-old GLL batch (free).
__global__ __launch_bounds__(128, 4)
void l1_main(const u32* __restrict__ qx, const u32* __restrict__ qw,
             const float* __restrict__ bias, float* __restrict__ out) {
  __shared__ __align__(16) unsigned char lds[16384];

  const int tid = threadIdx.x;
  const int lane = tid & 63;
  const int wv = tid >> 6;          // 0 or 1 (wave-uniform)
  const int tx = lane & 7;
  const int ty = lane >> 3;
  const int bo = blockIdx.x & 63;   // 64 o-tiles
  const int bn = blockIdx.x >> 6;   // 32 n-tiles
  const int n0 = bn * 64, o0 = bo * 64;

  // ---- staging source bases (per-lane, pre-permuted; verified R9/R13) ----
  const int lrow = lane >> 2;
  const int lslot = lane & 3;
  const int xkA = (lslot ^ ((lane >> 5) & 3)) << 2;
  const int xkB = (lslot ^ ((2 + (lane >> 5)) & 3)) << 2;
  const int wkk = (lslot ^ ((lane >> 3) & 3)) << 2;
  const u32* gx0 = qx + (size_t)(n0 + lrow) * K4;
  const u32* gw0 = qw + (size_t)(o0 + lrow) * K4;

  auto stage = [&](int kt, char* dst) {
    if (wv == 0) {
      GLL(gx0 + 0 * 16 * K4 + kt * 16 + xkA, dst);
      GLL(gx0 + 1 * 16 * K4 + kt * 16 + xkB, dst + 1024);
      GLL(gx0 + 2 * 16 * K4 + kt * 16 + xkA, dst + 2048);
      GLL(gx0 + 3 * 16 * K4 + kt * 16 + xkB, dst + 3072);
    } else {
      GLL(gw0 + 0 * 16 * K4 + kt * 16 + wkk, dst + 4096);
      GLL(gw0 + 1 * 16 * K4 + kt * 16 + wkk, dst + 5120);
      GLL(gw0 + 2 * 16 * K4 + kt * 16 + wkk, dst + 6144);
      GLL(gw0 + 3 * 16 * K4 + kt * 16 + wkk, dst + 7168);
    }
  };

  const int xkey = ty & 3;
  const int wkey = (tx >> 1) & 3;
  const int c0 = 2 * wv;            // this wave's first c-phase

  u32 acc[8][8];
#pragma unroll
  for (int i = 0; i < 8; ++i)
#pragma unroll
    for (int j = 0; j < 8; ++j) acc[i][j] = 0;

  u32x4 xv[8], wvv[8];

  auto ldxw = [&](const char* buf, int c) {
    const char* xb = buf + ty * 512 + (((c ^ xkey) & 3) << 4);
    const char* wb = buf + 4096 + tx * 64 + (((c ^ wkey) & 3) << 4);
#pragma unroll
    for (int i = 0; i < 8; ++i) xv[i] = *(const u32x4*)(xb + i * 64);
#pragma unroll
    for (int j = 0; j < 8; ++j) wvv[j] = *(const u32x4*)(wb + j * 512);
  };

  auto dosad = [&]() {
#pragma unroll
    for (int q = 0; q < 4; ++q)
#pragma unroll
      for (int i = 0; i < 8; ++i) {
        u32 xw = xv[i][q];
        acc[i][0] = sad_u8(xw, wvv[0][q], acc[i][0]);
        acc[i][1] = sad_u8(xw, wvv[1][q], acc[i][1]);
        acc[i][2] = sad_u8(xw, wvv[2][q], acc[i][2]);
        acc[i][3] = sad_u8(xw, wvv[3][q], acc[i][3]);
        acc[i][4] = sad_u8(xw, wvv[4][q], acc[i][4]);
        acc[i][5] = sad_u8(xw, wvv[5][q], acc[i][5]);
        acc[i][6] = sad_u8(xw, wvv[6][q], acc[i][6]);
        acc[i][7] = sad_u8(xw, wvv[7][q], acc[i][7]);
      }
  };

  char* b0 = (char*)lds;
  char* b1 = (char*)lds + 8192;

  // prologue
  stage(0, b0);
  __syncthreads();

#pragma unroll 1
  for (int kt = 0; kt < 16; ++kt) {
    char* buf = (kt & 1) ? b1 : b0;
    char* nbuf = (kt & 1) ? b0 : b1;
    if (kt < 15) stage(kt + 1, nbuf);  // 4 GLL per wave; retires under compute
    ldxw(buf, c0);
    dosad();
    ldxw(buf, c0 + 1);
    dosad();
    if (kt < 15) __syncthreads();      // implicit vmcnt(0): GLLs ~2000 cyc old
  }

  // ---- cross-wave split-K reduction (pair = same lane of the two waves) ----
  // region [0, 9216): row stride 144B (16-aligned; 2-way banks = free).
  char* red = (char*)lds;
  __syncthreads();                     // both waves done reading b0/b1
  if (wv == 1) {
#pragma unroll
    for (int r = 0; r < 4; ++r) {
      u32x4 a0 = {acc[r][0], acc[r][1], acc[r][2], acc[r][3]};
      u32x4 a1 = {acc[r][4], acc[r][5], acc[r][6], acc[r][7]};
      *(u32x4*)(red + lane * 144 + r * 32) = a0;
      *(u32x4*)(red + lane * 144 + r * 32 + 16) = a1;
    }
  }
  __syncthreads();
  if (wv == 0) {
#pragma unroll
    for (int r = 0; r < 4; ++r) {
      u32x4 a0 = *(const u32x4*)(red + lane * 144 + r * 32);
      u32x4 a1 = *(const u32x4*)(red + lane * 144 + r * 32 + 16);
#pragma unroll
      for (int j = 0; j < 4; ++j) {
        acc[r][j] += a0[j];
        acc[r][j + 4] += a1[j];
      }
    }
  }
  __syncthreads();
  if (wv == 0) {
#pragma unroll
    for (int r = 0; r < 4; ++r) {
      u32x4 a0 = {acc[r + 4][0], acc[r + 4][1], acc[r + 4][2], acc[r + 4][3]};
      u32x4 a1 = {acc[r + 4][4], acc[r + 4][5], acc[r + 4][6], acc[r + 4][7]};
      *(u32x4*)(red + lane * 144 + r * 32) = a0;
      *(u32x4*)(red + lane * 144 + r * 32 + 16) = a1;
    }
  }
  __syncthreads();
  if (wv == 1) {
#pragma unroll
    for (int r = 0; r < 4; ++r) {
      u32x4 a0 = *(const u32x4*)(red + lane * 144 + r * 32);
      u32x4 a1 = *(const u32x4*)(red + lane * 144 + r * 32 + 16);
#pragma unroll
      for (int j = 0; j < 4; ++j) {
        acc[r + 4][j] += a0[j];
        acc[r + 4][j + 4] += a1[j];
      }
    }
  }

  // epilogue: wave0 writes rows 0..3, wave1 rows 4..7; out = bias - acc/scale
  float bj[8];
#pragma unroll
  for (int j = 0; j < 8; ++j) bj[j] = bias[o0 + j * 8 + tx];
  const int i0 = wv * 4;
#pragma unroll
  for (int r = 0; r < 4; ++r) {
    const int i = i0 + r;
    float* orow = out + (size_t)(n0 + ty * 8 + i) * O_DIM + o0 + tx;
#pragma unroll
    for (int j = 0; j < 8; ++j)
      orow[j * 8] = fmaf((float)acc[i][j], -INVSCALE, bj[j]);
  }
}

// Correctness-only fallback if workspace is too small (not expected to run).
__global__ void l1_fallback(const float* __restrict__ x, const float* __restrict__ w,
                            const float* __restrict__ bias, float* __restrict__ out) {
  int t = blockIdx.x * blockDim.x + threadIdx.x;
  if (t >= N_ROWS * O_DIM) return;
  int n = t / O_DIM, o = t & (O_DIM - 1);
  const float* xr = x + (size_t)n * K_DIM;
  const float* wr = w + (size_t)o * K_DIM;
  float s = 0.f;
  for (int k = 0; k < K_DIM; ++k) s += fabsf(xr[k] - wr[k]);
  out[t] = bias[o] - s;
}

extern "C" void kernel_launch(void* const* d_in, const int* in_sizes, int n_in,
                              void* d_out, int out_size, void* d_ws, size_t ws_size,
                              hipStream_t stream) {
  const float* x = (const float*)d_in[0];     // (2,1024,1024) f32
  const float* w = (const float*)d_in[1];     // (4096,1024) f32
  const float* bias = (const float*)d_in[2];  // (4096,) f32
  float* out = (float*)d_out;                 // (2,1024,4096) f32

  const size_t qx_bytes = (size_t)XWORDS * 4;  // 2 MB
  const size_t qw_bytes = (size_t)WWORDS * 4;  // 4 MB

  if (ws_size >= qx_bytes + qw_bytes) {
    u32* qx = (u32*)d_ws;
    u32* qw = (u32*)((char*)d_ws + qx_bytes);
    const int totw = XWORDS + WWORDS;
    quant_both<<<(totw + 255) / 256, 256, 0, stream>>>(x, w, qx, qw);
    l1_main<<<2048, 128, 0, stream>>>(qx, qw, bias, out);
  } else {
    l1_fallback<<<(N_ROWS * O_DIM + 255) / 256, 256, 0, stream>>>(x, w, bias, out);
  }
}

// Round 15
// 192.461 us; speedup vs baseline: 1.0418x; 1.0418x over previous
//
#include <hip/hip_runtime.h>

typedef unsigned int u32;
typedef u32 u32x2 __attribute__((ext_vector_type(2)));
typedef u32 u32x4 __attribute__((ext_vector_type(4)));
typedef float f32x4 __attribute__((ext_vector_type(4)));

#define N_ROWS 2048
#define K_DIM  1024
#define K4     256          // u32 words per row
#define O_DIM  4096

#define QSCALE   23.090909f      // 127 / 5.5
#define QBIAS    128.5f          // +128 bias, +0.5 for round via trunc
#define INVSCALE (5.5f / 127.0f)

#define XWORDS (N_ROWS * K4)     // 524288 u32 (2 MB)
#define WWORDS (O_DIM * K4)      // 1048576 u32 (4 MB)

// v_sad_u8: D = sum_{i<4} |S0.byte[i] - S1.byte[i]| + S2  (4 cyc/wave-instr)
__device__ __forceinline__ u32 sad_u8(u32 a, u32 b, u32 c) {
  u32 d;
  asm("v_sad_u8 %0, %1, %2, %3" : "=v"(d) : "v"(a), "v"(b), "v"(c));
  return d;
}

__device__ __forceinline__ u32 quant4(f32x4 v) {
  u32 b0 = (u32)fminf(fmaxf(fmaf(v[0], QSCALE, QBIAS), 0.f), 255.f);
  u32 b1 = (u32)fminf(fmaxf(fmaf(v[1], QSCALE, QBIAS), 0.f), 255.f);
  u32 b2 = (u32)fminf(fmaxf(fmaf(v[2], QSCALE, QBIAS), 0.f), 255.f);
  u32 b3 = (u32)fminf(fmaxf(fmaf(v[3], QSCALE, QBIAS), 0.f), 255.f);
  return b0 | (b1 << 8) | (b2 << 16) | (b3 << 24);
}

__global__ void quant_both(const float* __restrict__ x, const float* __restrict__ w,
                           u32* __restrict__ qx, u32* __restrict__ qw) {
  int i = blockIdx.x * blockDim.x + threadIdx.x;
  if (i < XWORDS)
    qx[i] = quant4(((const f32x4*)x)[i]);
  else if (i < XWORDS + WWORDS)
    qw[i - XWORDS] = quant4(((const f32x4*)w)[i - XWORDS]);
}

#define GLL(src, dst)                                                     \
  __builtin_amdgcn_global_load_lds(                                       \
      (const __attribute__((address_space(1))) void*)(src),               \
      (__attribute__((address_space(3))) void*)(dst), 16, 0, 0)

// 2-wave blocks (128 thr), ONE 64n x 64o tile per block, thread tile 8x8
// (tx=lane&7, ty=lane>>3). Split-K: wave wv computes 8-byte phases
// {4wv..4wv+3} of each kt (KC=64B); partials merged via LDS at the end.
// Grid 2048 -> 4096 waves = 4 waves/SIMD. Operands are ds_read_b64 (u32x2):
// acc 64 + xv 16 + wv 16 + addr ~= 115 VGPR < 128 cap (launch_bounds(128,2):
// R14 showed the 2nd arg multiplies per-block waves -> 2*2=4 waves/EU -> 128).
// R14's failure was this cap at 64 -> acc spilled (WRITE_SIZE 1.16 GB).
// LDS: 2 bufs x 8KB (x 4KB rows 64B | w 4KB rows 64B), 16 kts.
// Swizzle (verified 0 conflicts R9/R13): LDS[r][s] = G[r][s ^ key(r)], s=16B slot;
//   x key (r>>3)&3 (read: ty&3), w key (r>>1)&3 (read: (tx>>1)&3).
// b64 phase p: slot s=p>>1, byte-half h=(p&1)*8. Banks: w-phase 8 distinct x2
// broadcast; x-phase 2 addrs -> conflict-free.
// Staging: wave0 stages x (4 GLL), wave1 stages w (4 GLL); one __syncthreads
// per kt AFTER compute (implicit vmcnt(0) drains ~2500-cyc-old GLLs -> free).
__global__ __launch_bounds__(128, 2)
void l1_main(const u32* __restrict__ qx, const u32* __restrict__ qw,
             const float* __restrict__ bias, float* __restrict__ out) {
  __shared__ __align__(16) unsigned char lds[16384];

  const int tid = threadIdx.x;
  const int lane = tid & 63;
  const int wv = tid >> 6;          // 0 or 1 (wave-uniform)
  const int tx = lane & 7;
  const int ty = lane >> 3;
  const int bo = blockIdx.x & 63;   // 64 o-tiles
  const int bn = blockIdx.x >> 6;   // 32 n-tiles
  const int n0 = bn * 64, o0 = bo * 64;

  // ---- staging source bases (per-lane, pre-permuted; verified R9/R13) ----
  const int lrow = lane >> 2;
  const int lslot = lane & 3;
  const int xkA = (lslot ^ ((lane >> 5) & 3)) << 2;
  const int xkB = (lslot ^ ((2 + (lane >> 5)) & 3)) << 2;
  const int wkk = (lslot ^ ((lane >> 3) & 3)) << 2;
  const u32* gx0 = qx + (size_t)(n0 + lrow) * K4;
  const u32* gw0 = qw + (size_t)(o0 + lrow) * K4;

  auto stage = [&](int kt, char* dst) {
    if (wv == 0) {
      GLL(gx0 + 0 * 16 * K4 + kt * 16 + xkA, dst);
      GLL(gx0 + 1 * 16 * K4 + kt * 16 + xkB, dst + 1024);
      GLL(gx0 + 2 * 16 * K4 + kt * 16 + xkA, dst + 2048);
      GLL(gx0 + 3 * 16 * K4 + kt * 16 + xkB, dst + 3072);
    } else {
      GLL(gw0 + 0 * 16 * K4 + kt * 16 + wkk, dst + 4096);
      GLL(gw0 + 1 * 16 * K4 + kt * 16 + wkk, dst + 5120);
      GLL(gw0 + 2 * 16 * K4 + kt * 16 + wkk, dst + 6144);
      GLL(gw0 + 3 * 16 * K4 + kt * 16 + wkk, dst + 7168);
    }
  };

  const int xkey = ty & 3;
  const int wkey = (tx >> 1) & 3;
  const int p0 = 4 * wv;            // this wave's first 8B phase

  u32 acc[8][8];
#pragma unroll
  for (int i = 0; i < 8; ++i)
#pragma unroll
    for (int j = 0; j < 8; ++j) acc[i][j] = 0;

  // one phase: 16 ds_read_b64 + 128 sads
  auto ph = [&](const char* buf, int p) {
    const int s = p >> 1;
    const int h = (p & 1) * 8;
    const char* xb = buf + ty * 512 + (((s ^ xkey) & 3) << 4) + h;
    const char* wb = buf + 4096 + tx * 64 + (((s ^ wkey) & 3) << 4) + h;
    u32x2 xv[8], wvv[8];
#pragma unroll
    for (int i = 0; i < 8; ++i) xv[i] = *(const u32x2*)(xb + i * 64);
#pragma unroll
    for (int j = 0; j < 8; ++j) wvv[j] = *(const u32x2*)(wb + j * 512);
#pragma unroll
    for (int q = 0; q < 2; ++q)
#pragma unroll
      for (int i = 0; i < 8; ++i) {
        u32 xw = xv[i][q];
        acc[i][0] = sad_u8(xw, wvv[0][q], acc[i][0]);
        acc[i][1] = sad_u8(xw, wvv[1][q], acc[i][1]);
        acc[i][2] = sad_u8(xw, wvv[2][q], acc[i][2]);
        acc[i][3] = sad_u8(xw, wvv[3][q], acc[i][3]);
        acc[i][4] = sad_u8(xw, wvv[4][q], acc[i][4]);
        acc[i][5] = sad_u8(xw, wvv[5][q], acc[i][5]);
        acc[i][6] = sad_u8(xw, wvv[6][q], acc[i][6]);
        acc[i][7] = sad_u8(xw, wvv[7][q], acc[i][7]);
      }
  };

  char* b0 = (char*)lds;
  char* b1 = (char*)lds + 8192;

  // prologue
  stage(0, b0);
  __syncthreads();

#pragma unroll 1
  for (int kt = 0; kt < 16; ++kt) {
    char* buf = (kt & 1) ? b1 : b0;
    char* nbuf = (kt & 1) ? b0 : b1;
    if (kt < 15) stage(kt + 1, nbuf);  // 4 GLL per wave; retires under compute
    ph(buf, p0);
    ph(buf, p0 + 1);
    ph(buf, p0 + 2);
    ph(buf, p0 + 3);
    if (kt < 15) __syncthreads();      // implicit vmcnt(0): GLLs ~2500 cyc old
  }

  // ---- cross-wave split-K reduction (pair = same lane of the two waves) ----
  // region [0, 9216): row stride 144B -> bank word 4*lane mod 32 -> 2-way (free).
  char* red = (char*)lds;
  __syncthreads();                     // both waves done reading b0/b1
  if (wv == 1) {
#pragma unroll
    for (int r = 0; r < 4; ++r) {
      u32x4 a0 = {acc[r][0], acc[r][1], acc[r][2], acc[r][3]};
      u32x4 a1 = {acc[r][4], acc[r][5], acc[r][6], acc[r][7]};
      *(u32x4*)(red + lane * 144 + r * 32) = a0;
      *(u32x4*)(red + lane * 144 + r * 32 + 16) = a1;
    }
  }
  __syncthreads();
  if (wv == 0) {
#pragma unroll
    for (int r = 0; r < 4; ++r) {
      u32x4 a0 = *(const u32x4*)(red + lane * 144 + r * 32);
      u32x4 a1 = *(const u32x4*)(red + lane * 144 + r * 32 + 16);
#pragma unroll
      for (int j = 0; j < 4; ++j) {
        acc[r][j] += a0[j];
        acc[r][j + 4] += a1[j];
      }
    }
  }
  __syncthreads();
  if (wv == 0) {
#pragma unroll
    for (int r = 0; r < 4; ++r) {
      u32x4 a0 = {acc[r + 4][0], acc[r + 4][1], acc[r + 4][2], acc[r + 4][3]};
      u32x4 a1 = {acc[r + 4][4], acc[r + 4][5], acc[r + 4][6], acc[r + 4][7]};
      *(u32x4*)(red + lane * 144 + r * 32) = a0;
      *(u32x4*)(red + lane * 144 + r * 32 + 16) = a1;
    }
  }
  __syncthreads();
  if (wv == 1) {
#pragma unroll
    for (int r = 0; r < 4; ++r) {
      u32x4 a0 = *(const u32x4*)(red + lane * 144 + r * 32);
      u32x4 a1 = *(const u32x4*)(red + lane * 144 + r * 32 + 16);
#pragma unroll
      for (int j = 0; j < 4; ++j) {
        acc[r + 4][j] += a0[j];
        acc[r + 4][j + 4] += a1[j];
      }
    }
  }

  // epilogue: wave0 writes rows 0..3, wave1 rows 4..7; out = bias - acc/scale
  float bj[8];
#pragma unroll
  for (int j = 0; j < 8; ++j) bj[j] = bias[o0 + j * 8 + tx];
  const int i0 = wv * 4;
#pragma unroll
  for (int r = 0; r < 4; ++r) {
    const int i = i0 + r;
    float* orow = out + (size_t)(n0 + ty * 8 + i) * O_DIM + o0 + tx;
#pragma unroll
    for (int j = 0; j < 8; ++j)
      orow[j * 8] = fmaf((float)acc[i][j], -INVSCALE, bj[j]);
  }
}

// Correctness-only fallback if workspace is too small (not expected to run).
__global__ void l1_fallback(const float* __restrict__ x, const float* __restrict__ w,
                            const float* __restrict__ bias, float* __restrict__ out) {
  int t = blockIdx.x * blockDim.x + threadIdx.x;
  if (t >= N_ROWS * O_DIM) return;
  int n = t / O_DIM, o = t & (O_DIM - 1);
  const float* xr = x + (size_t)n * K_DIM;
  const float* wr = w + (size_t)o * K_DIM;
  float s = 0.f;
  for (int k = 0; k < K_DIM; ++k) s += fabsf(xr[k] - wr[k]);
  out[t] = bias[o] - s;
}

extern "C" void kernel_launch(void* const* d_in, const int* in_sizes, int n_in,
                              void* d_out, int out_size, void* d_ws, size_t ws_size,
                              hipStream_t stream) {
  const float* x = (const float*)d_in[0];     // (2,1024,1024) f32
  const float* w = (const float*)d_in[1];     // (4096,1024) f32
  const float* bias = (const float*)d_in[2];  // (4096,) f32
  float* out = (float*)d_out;                 // (2,1024,4096) f32

  const size_t qx_bytes = (size_t)XWORDS * 4;  // 2 MB
  const size_t qw_bytes = (size_t)WWORDS * 4;  // 4 MB

  if (ws_size >= qx_bytes + qw_bytes) {
    u32* qx = (u32*)d_ws;
    u32* qw = (u32*)((char*)d_ws + qx_bytes);
    const int totw = XWORDS + WWORDS;
    quant_both<<<(totw + 255) / 256, 256, 0, stream>>>(x, w, qx, qw);
    l1_main<<<2048, 128, 0, stream>>>(qx, qw, bias, out);
  } else {
    l1_fallback<<<(N_ROWS * O_DIM + 255) / 256, 256, 0, stream>>>(x, w, bias, out);
  }
}

// Round 16
// 104.104 us; speedup vs baseline: 1.9259x; 1.8487x over previous
//
#include <hip/hip_runtime.h>

typedef unsigned int u32;
typedef u32 u32x2 __attribute__((ext_vector_type(2)));
typedef u32 u32x4 __attribute__((ext_vector_type(4)));
typedef float f32x4 __attribute__((ext_vector_type(4)));

#define N_ROWS 2048
#define K_DIM  1024
#define K4     256          // u32 words per row
#define O_DIM  4096

#define QSCALE   23.090909f      // 127 / 5.5
#define QBIAS    128.5f          // +128 bias, +0.5 for round via trunc
#define INVSCALE (5.5f / 127.0f)

#define XWORDS (N_ROWS * K4)     // 524288 u32 (2 MB)
#define WWORDS (O_DIM * K4)      // 1048576 u32 (4 MB)

// v_sad_u8: D = sum_{i<4} |S0.byte[i] - S1.byte[i]| + S2  (4 cyc/wave-instr)
__device__ __forceinline__ u32 sad_u8(u32 a, u32 b, u32 c) {
  u32 d;
  asm("v_sad_u8 %0, %1, %2, %3" : "=v"(d) : "v"(a), "v"(b), "v"(c));
  return d;
}

__device__ __forceinline__ u32 quant4(f32x4 v) {
  u32 b0 = (u32)fminf(fmaxf(fmaf(v[0], QSCALE, QBIAS), 0.f), 255.f);
  u32 b1 = (u32)fminf(fmaxf(fmaf(v[1], QSCALE, QBIAS), 0.f), 255.f);
  u32 b2 = (u32)fminf(fmaxf(fmaf(v[2], QSCALE, QBIAS), 0.f), 255.f);
  u32 b3 = (u32)fminf(fmaxf(fmaf(v[3], QSCALE, QBIAS), 0.f), 255.f);
  return b0 | (b1 << 8) | (b2 << 16) | (b3 << 24);
}

__global__ void quant_both(const float* __restrict__ x, const float* __restrict__ w,
                           u32* __restrict__ qx, u32* __restrict__ qw) {
  int i = blockIdx.x * blockDim.x + threadIdx.x;
  if (i < XWORDS)
    qx[i] = quant4(((const f32x4*)x)[i]);
  else if (i < XWORDS + WWORDS)
    qw[i - XWORDS] = quant4(((const f32x4*)w)[i - XWORDS]);
}

#define GLL(src, dst)                                                     \
  __builtin_amdgcn_global_load_lds(                                       \
      (const __attribute__((address_space(1))) void*)(src),               \
      (__attribute__((address_space(3))) void*)(dst), 16, 0, 0)

// 2-wave blocks (128 thr), ONE 64n x 64o tile per block, thread tile 8x8
// (tx=lane&7, ty=lane>>3). Split-K: wave wv computes 8-byte phases
// {4wv..4wv+3} of each kt (KC=64B); partials merged via LDS at the end.
// Grid 2048 -> 4096 waves = 4 waves/SIMD.
// R14/R15 FAILURE ROOT CAUSE (rule #20): epilogue indexed acc[wv*4+r] with
// runtime wv -> entire acc array in SCRATCH -> 1.1 GB writes, 200 us. Fixed:
// every acc access is now compile-time static (wave-uniform branch instead).
// LDS: 2 bufs x 8KB (x 4KB rows 64B | w 4KB rows 64B), 16 kts.
// Swizzle (verified 0 conflicts R9/R13): LDS[r][s] = G[r][s ^ key(r)], s=16B slot;
//   x key (r>>3)&3 (read: ty&3), w key (r>>1)&3 (read: (tx>>1)&3).
// b64 phase p: slot s=p>>1, byte-half h=(p&1)*8 -> conflict-free (w: 8 banks x2
// broadcast; x: 2 addrs).
// Staging: wave0 stages x (4 GLL), wave1 stages w (4 GLL); one __syncthreads
// per kt AFTER compute (implicit vmcnt(0) drains ~2500-cyc-old GLLs -> free).
__global__ __launch_bounds__(128, 2)
void l1_main(const u32* __restrict__ qx, const u32* __restrict__ qw,
             const float* __restrict__ bias, float* __restrict__ out) {
  __shared__ __align__(16) unsigned char lds[16384];

  const int tid = threadIdx.x;
  const int lane = tid & 63;
  const int wv = tid >> 6;          // 0 or 1 (wave-uniform)
  const int tx = lane & 7;
  const int ty = lane >> 3;
  const int bo = blockIdx.x & 63;   // 64 o-tiles
  const int bn = blockIdx.x >> 6;   // 32 n-tiles
  const int n0 = bn * 64, o0 = bo * 64;

  // ---- staging source bases (per-lane, pre-permuted; verified R9/R13) ----
  const int lrow = lane >> 2;
  const int lslot = lane & 3;
  const int xkA = (lslot ^ ((lane >> 5) & 3)) << 2;
  const int xkB = (lslot ^ ((2 + (lane >> 5)) & 3)) << 2;
  const int wkk = (lslot ^ ((lane >> 3) & 3)) << 2;
  const u32* gx0 = qx + (size_t)(n0 + lrow) * K4;
  const u32* gw0 = qw + (size_t)(o0 + lrow) * K4;

  auto stage = [&](int kt, char* dst) {
    if (wv == 0) {
      GLL(gx0 + 0 * 16 * K4 + kt * 16 + xkA, dst);
      GLL(gx0 + 1 * 16 * K4 + kt * 16 + xkB, dst + 1024);
      GLL(gx0 + 2 * 16 * K4 + kt * 16 + xkA, dst + 2048);
      GLL(gx0 + 3 * 16 * K4 + kt * 16 + xkB, dst + 3072);
    } else {
      GLL(gw0 + 0 * 16 * K4 + kt * 16 + wkk, dst + 4096);
      GLL(gw0 + 1 * 16 * K4 + kt * 16 + wkk, dst + 5120);
      GLL(gw0 + 2 * 16 * K4 + kt * 16 + wkk, dst + 6144);
      GLL(gw0 + 3 * 16 * K4 + kt * 16 + wkk, dst + 7168);
    }
  };

  const int xkey = ty & 3;
  const int wkey = (tx >> 1) & 3;
  const int p0 = 4 * wv;            // this wave's first 8B phase (addr-only)

  u32 acc[8][8];
#pragma unroll
  for (int i = 0; i < 8; ++i)
#pragma unroll
    for (int j = 0; j < 8; ++j) acc[i][j] = 0;

  // one phase: 16 ds_read_b64 + 128 sads (p used only in address arithmetic)
  auto ph = [&](const char* buf, int p) {
    const int s = p >> 1;
    const int h = (p & 1) * 8;
    const char* xb = buf + ty * 512 + (((s ^ xkey) & 3) << 4) + h;
    const char* wb = buf + 4096 + tx * 64 + (((s ^ wkey) & 3) << 4) + h;
    u32x2 xv[8], wvv[8];
#pragma unroll
    for (int i = 0; i < 8; ++i) xv[i] = *(const u32x2*)(xb + i * 64);
#pragma unroll
    for (int j = 0; j < 8; ++j) wvv[j] = *(const u32x2*)(wb + j * 512);
#pragma unroll
    for (int q = 0; q < 2; ++q)
#pragma unroll
      for (int i = 0; i < 8; ++i) {
        u32 xw = xv[i][q];
        acc[i][0] = sad_u8(xw, wvv[0][q], acc[i][0]);
        acc[i][1] = sad_u8(xw, wvv[1][q], acc[i][1]);
        acc[i][2] = sad_u8(xw, wvv[2][q], acc[i][2]);
        acc[i][3] = sad_u8(xw, wvv[3][q], acc[i][3]);
        acc[i][4] = sad_u8(xw, wvv[4][q], acc[i][4]);
        acc[i][5] = sad_u8(xw, wvv[5][q], acc[i][5]);
        acc[i][6] = sad_u8(xw, wvv[6][q], acc[i][6]);
        acc[i][7] = sad_u8(xw, wvv[7][q], acc[i][7]);
      }
  };

  char* b0 = (char*)lds;
  char* b1 = (char*)lds + 8192;

  // prologue
  stage(0, b0);
  __syncthreads();

#pragma unroll 1
  for (int kt = 0; kt < 16; ++kt) {
    char* buf = (kt & 1) ? b1 : b0;
    char* nbuf = (kt & 1) ? b0 : b1;
    if (kt < 15) stage(kt + 1, nbuf);  // 4 GLL per wave; retires under compute
    ph(buf, p0);
    ph(buf, p0 + 1);
    ph(buf, p0 + 2);
    ph(buf, p0 + 3);
    if (kt < 15) __syncthreads();      // implicit vmcnt(0): GLLs ~2500 cyc old
  }

  // ---- cross-wave split-K reduction (all acc indices STATIC) ----
  // region rows stride 144B -> 2-way banks (free).
  char* red = (char*)lds;
  __syncthreads();                     // both waves done reading b0/b1
  if (wv == 1) {
#pragma unroll
    for (int r = 0; r < 4; ++r) {
      u32x4 a0 = {acc[r][0], acc[r][1], acc[r][2], acc[r][3]};
      u32x4 a1 = {acc[r][4], acc[r][5], acc[r][6], acc[r][7]};
      *(u32x4*)(red + lane * 144 + r * 32) = a0;
      *(u32x4*)(red + lane * 144 + r * 32 + 16) = a1;
    }
  }
  __syncthreads();
  if (wv == 0) {
#pragma unroll
    for (int r = 0; r < 4; ++r) {
      u32x4 a0 = *(const u32x4*)(red + lane * 144 + r * 32);
      u32x4 a1 = *(const u32x4*)(red + lane * 144 + r * 32 + 16);
#pragma unroll
      for (int j = 0; j < 4; ++j) {
        acc[r][j] += a0[j];
        acc[r][j + 4] += a1[j];
      }
    }
  }
  __syncthreads();
  if (wv == 0) {
#pragma unroll
    for (int r = 0; r < 4; ++r) {
      u32x4 a0 = {acc[r + 4][0], acc[r + 4][1], acc[r + 4][2], acc[r + 4][3]};
      u32x4 a1 = {acc[r + 4][4], acc[r + 4][5], acc[r + 4][6], acc[r + 4][7]};
      *(u32x4*)(red + lane * 144 + r * 32) = a0;
      *(u32x4*)(red + lane * 144 + r * 32 + 16) = a1;
    }
  }
  __syncthreads();
  if (wv == 1) {
#pragma unroll
    for (int r = 0; r < 4; ++r) {
      u32x4 a0 = *(const u32x4*)(red + lane * 144 + r * 32);
      u32x4 a1 = *(const u32x4*)(red + lane * 144 + r * 32 + 16);
#pragma unroll
      for (int j = 0; j < 4; ++j) {
        acc[r + 4][j] += a0[j];
        acc[r + 4][j + 4] += a1[j];
      }
    }
  }

  // epilogue (STATIC acc indices per wave-uniform branch; rule #20 fix):
  // wave0 writes rows 0..3 (acc[0..3]), wave1 rows 4..7 (acc[4..7]).
  float bj[8];
#pragma unroll
  for (int j = 0; j < 8; ++j) bj[j] = bias[o0 + j * 8 + tx];
  if (wv == 0) {
#pragma unroll
    for (int r = 0; r < 4; ++r) {
      float* orow = out + (size_t)(n0 + ty * 8 + r) * O_DIM + o0 + tx;
#pragma unroll
      for (int j = 0; j < 8; ++j)
        orow[j * 8] = fmaf((float)acc[r][j], -INVSCALE, bj[j]);
    }
  } else {
#pragma unroll
    for (int r = 0; r < 4; ++r) {
      float* orow = out + (size_t)(n0 + ty * 8 + 4 + r) * O_DIM + o0 + tx;
#pragma unroll
      for (int j = 0; j < 8; ++j)
        orow[j * 8] = fmaf((float)acc[r + 4][j], -INVSCALE, bj[j]);
    }
  }
}

// Correctness-only fallback if workspace is too small (not expected to run).
__global__ void l1_fallback(const float* __restrict__ x, const float* __restrict__ w,
                            const float* __restrict__ bias, float* __restrict__ out) {
  int t = blockIdx.x * blockDim.x + threadIdx.x;
  if (t >= N_ROWS * O_DIM) return;
  int n = t / O_DIM, o = t & (O_DIM - 1);
  const float* xr = x + (size_t)n * K_DIM;
  const float* wr = w + (size_t)o * K_DIM;
  float s = 0.f;
  for (int k = 0; k < K_DIM; ++k) s += fabsf(xr[k] - wr[k]);
  out[t] = bias[o] - s;
}

extern "C" void kernel_launch(void* const* d_in, const int* in_sizes, int n_in,
                              void* d_out, int out_size, void* d_ws, size_t ws_size,
                              hipStream_t stream) {
  const float* x = (const float*)d_in[0];     // (2,1024,1024) f32
  const float* w = (const float*)d_in[1];     // (4096,1024) f32
  const float* bias = (const float*)d_in[2];  // (4096,) f32
  float* out = (float*)d_out;                 // (2,1024,4096) f32

  const size_t qx_bytes = (size_t)XWORDS * 4;  // 2 MB
  const size_t qw_bytes = (size_t)WWORDS * 4;  // 4 MB

  if (ws_size >= qx_bytes + qw_bytes) {
    u32* qx = (u32*)d_ws;
    u32* qw = (u32*)((char*)d_ws + qx_bytes);
    const int totw = XWORDS + WWORDS;
    quant_both<<<(totw + 255) / 256, 256, 0, stream>>>(x, w, qx, qw);
    l1_main<<<2048, 128, 0, stream>>>(qx, qw, bias, out);
  } else {
    l1_fallback<<<(N_ROWS * O_DIM + 255) / 256, 256, 0, stream>>>(x, w, bias, out);
  }
}